// Round 1
// baseline (71.582 us; speedup 1.0000x reference)
//
#include <hip/hip_runtime.h>

#define BB 2
#define CC 64
#define CI 32
#define NPIX 9216   // 96*96
#define TN 128

// ---------------------------------------------------------------------------
// k1: per-(batch,chunk) partial S = X X^T (64x64) and r = X @ 1 (64)
// ---------------------------------------------------------------------------
__global__ __launch_bounds__(256) void k1_stats(
    const float* __restrict__ x, float* __restrict__ Spart,
    float* __restrict__ rpart, int nch, int chunk) {
  const int blk = blockIdx.x;
  const int batch = blk / nch;
  const int chk = blk - batch * nch;
  const float* __restrict__ X =
      x + (size_t)batch * CC * NPIX + (size_t)chk * chunk;
  const int t = threadIdx.x;
  const int colL = t & 15;   // column within 16-col stage / output j-tile
  const int rowL = t >> 4;   // channel group / output i-tile
  const int i0 = rowL * 4;
  const int j0 = colL * 4;
  __shared__ float tile[16][68];  // [col][channel], padded (bank-safe)
  float acc[4][4] = {};
  float racc[4] = {0.f, 0.f, 0.f, 0.f};

  for (int s = 0; s < chunk; s += 16) {
#pragma unroll
    for (int j = 0; j < 4; ++j) {
      const int c = rowL + 16 * j;
      const float v = X[(size_t)c * NPIX + s + colL];
      tile[colL][c] = v;
      racc[j] += v;
    }
    __syncthreads();
#pragma unroll
    for (int n = 0; n < 16; ++n) {
      const float4 av = *reinterpret_cast<const float4*>(&tile[n][i0]);
      const float4 bv = *reinterpret_cast<const float4*>(&tile[n][j0]);
      const float a[4] = {av.x, av.y, av.z, av.w};
      const float b[4] = {bv.x, bv.y, bv.z, bv.w};
#pragma unroll
      for (int ii = 0; ii < 4; ++ii)
#pragma unroll
        for (int jj = 0; jj < 4; ++jj) acc[ii][jj] += a[ii] * b[jj];
    }
    __syncthreads();
  }

  float* Sp = Spart + (size_t)blk * (CC * CC);
#pragma unroll
  for (int ii = 0; ii < 4; ++ii) {
    float4 v4 = make_float4(acc[ii][0], acc[ii][1], acc[ii][2], acc[ii][3]);
    *reinterpret_cast<float4*>(&Sp[(i0 + ii) * CC + j0]) = v4;
  }
  // reduce row-sum partials across the 16 column-lanes
#pragma unroll
  for (int j = 0; j < 4; ++j) {
    float v = racc[j];
    v += __shfl_down(v, 8, 16);
    v += __shfl_down(v, 4, 16);
    v += __shfl_down(v, 2, 16);
    v += __shfl_down(v, 1, 16);
    if (colL == 0) rpart[(size_t)blk * CC + rowL + 16 * j] = v;
  }
}

// ---------------------------------------------------------------------------
// k_reduce: fold chunk partials into final S (B x 64 x 64) and r (B x 64)
// ---------------------------------------------------------------------------
__global__ __launch_bounds__(256) void k_reduce(
    const float* __restrict__ Spart, const float* __restrict__ rpart,
    float* __restrict__ S, float* __restrict__ r, int nch) {
  const int blk = blockIdx.x;   // BB*16
  const int batch = blk >> 4;
  const int part = blk & 15;
  const int idx = part * 256 + threadIdx.x;
  float s = 0.f;
  for (int k = 0; k < nch; ++k)
    s += Spart[((size_t)(batch * nch + k)) * (CC * CC) + idx];
  S[batch * (CC * CC) + idx] = s;
  if (part == 0 && threadIdx.x < CC) {
    float rs = 0.f;
    for (int k = 0; k < nch; ++k)
      rs += rpart[((size_t)(batch * nch + k)) * CC + threadIdx.x];
    r[batch * CC + threadIdx.x] = rs;
  }
}

// ---------------------------------------------------------------------------
// k2: per-batch tiny algebra:
//   M   = pw S gw^T + (pw r) gb^T + pb (gw r)^T + N pb gb^T   (32x32)
//   W_b = rw M^T tw / N                                       (64x64)
//   b_b = rw (M^T tb) / N + rb                                (64)
// ---------------------------------------------------------------------------
__global__ __launch_bounds__(256) void k2_weights(
    const float* __restrict__ S_g, const float* __restrict__ r_g,
    const float* __restrict__ tw, const float* __restrict__ tb,
    const float* __restrict__ pw, const float* __restrict__ pb,
    const float* __restrict__ gw, const float* __restrict__ gb,
    const float* __restrict__ rw, const float* __restrict__ rb,
    float* __restrict__ Wc, float* __restrict__ bc) {
  const int b = blockIdx.x;
  const int t = threadIdx.x;
  __shared__ float S[CC][CC + 1];
  __shared__ float Gt[CC][CI + 1];   // gw transposed: Gt[j][c] = gw[c*CC+j]
  __shared__ float r[CC];
  __shared__ float A[CI][CC + 1];    // pw @ S
  __shared__ float M[CI][CI + 1];
  __shared__ float T1[CI][CC + 1];   // (M^T tw)[c][j]
  __shared__ float u[CI], v[CI], t2[CI];

  for (int idx = t; idx < CC * CC; idx += 256)
    S[idx >> 6][idx & 63] = S_g[b * CC * CC + idx];
  for (int idx = t; idx < CI * CC; idx += 256) {
    int c = idx >> 6, j = idx & 63;
    Gt[j][c] = gw[idx];
  }
  if (t < CC) r[t] = r_g[b * CC + t];
  __syncthreads();

  if (t < CI) {
    float s = 0.f;
    for (int i = 0; i < CC; ++i) s += gw[t * CC + i] * r[i];
    u[t] = s;
  } else if (t < 2 * CI) {
    const int k = t - CI;
    float s = 0.f;
    for (int i = 0; i < CC; ++i) s += pw[k * CC + i] * r[i];
    v[k] = s;
  }
  // A[k][j] = sum_i pw[k][i] S[i][j]
  for (int o = t; o < CI * CC; o += 256) {
    const int k = o >> 6, j = o & 63;
    float s = 0.f;
    for (int i = 0; i < CC; ++i) s += pw[k * CC + i] * S[i][j];
    A[k][j] = s;
  }
  __syncthreads();

  // M[k][c] = sum_j A[k][j] gw[c][j] + v[k] gb[c] + pb[k] u[c] + N pb[k] gb[c]
  for (int o = t; o < CI * CI; o += 256) {
    const int k = o >> 5, c = o & 31;
    float s = 0.f;
    for (int j = 0; j < CC; ++j) s += A[k][j] * Gt[j][c];
    s += v[k] * gb[c] + pb[k] * u[c] + (float)NPIX * pb[k] * gb[c];
    M[k][c] = s;
  }
  __syncthreads();

  // T1[c][j] = sum_k M[k][c] tw[k][j];  t2[c] = sum_k M[k][c] tb[k]
  for (int o = t; o < CI * CC; o += 256) {
    const int c = o >> 6, j = o & 63;
    float s = 0.f;
    for (int k = 0; k < CI; ++k) s += M[k][c] * tw[k * CC + j];
    T1[c][j] = s;
  }
  if (t < CI) {
    float s = 0.f;
    for (int k = 0; k < CI; ++k) s += M[k][t] * tb[k];
    t2[t] = s;
  }
  __syncthreads();

  const float invN = 1.0f / (float)NPIX;
  // W[o][j] = invN * sum_c rw[o][c] T1[c][j]
  for (int o = t; o < CC * CC; o += 256) {
    const int oc = o >> 6, j = o & 63;
    float s = 0.f;
    for (int c = 0; c < CI; ++c) s += rw[oc * CI + c] * T1[c][j];
    Wc[b * CC * CC + o] = s * invN;
  }
  if (t < CC) {
    float s = 0.f;
    for (int c = 0; c < CI; ++c) s += rw[t * CI + c] * t2[c];
    bc[b * CC + t] = s * invN + rb[t];
  }
}

// ---------------------------------------------------------------------------
// k3: Z = X + W_b X + b_b   (64x64 @ 64xN GEMM + residual, streaming)
// ---------------------------------------------------------------------------
__global__ __launch_bounds__(256) void k3_apply(
    const float* __restrict__ x, const float* __restrict__ Wc,
    const float* __restrict__ bc, float* __restrict__ z) {
  const int nblk = NPIX / TN;  // 72
  const int blk = blockIdx.x;
  const int batch = blk / nblk;
  const int nb = blk - batch * nblk;
  const int n0 = nb * TN;
  const float* __restrict__ X = x + (size_t)batch * CC * NPIX;
  float* __restrict__ Z = z + (size_t)batch * CC * NPIX;
  const float* __restrict__ W = Wc + (size_t)batch * CC * CC;
  const int t = threadIdx.x;
  __shared__ float Wt[CC][68];     // Wt[k][c] = W[c][k]
  __shared__ float xt[CC][TN];
  __shared__ float bl[CC];

  for (int idx = t; idx < CC * CC; idx += 256) {
    const int c = idx >> 6, k = idx & 63;
    Wt[k][c] = W[idx];
  }
  for (int idx = t; idx < CC * TN; idx += 256) {
    const int k = idx >> 7, n = idx & (TN - 1);
    xt[k][n] = X[(size_t)k * NPIX + n0 + n];
  }
  if (t < CC) bl[t] = bc[batch * CC + t];
  __syncthreads();

  const int c0 = (t >> 5) * 8;    // 8 channels per thread
  const int m0 = (t & 31) * 4;    // 4 columns per thread
  float acc[8][4] = {};
#pragma unroll 4
  for (int k = 0; k < CC; ++k) {
    const float4 xv = *reinterpret_cast<const float4*>(&xt[k][m0]);
    const float4 w0 = *reinterpret_cast<const float4*>(&Wt[k][c0]);
    const float4 w1 = *reinterpret_cast<const float4*>(&Wt[k][c0 + 4]);
    const float xa[4] = {xv.x, xv.y, xv.z, xv.w};
    const float wa[8] = {w0.x, w0.y, w0.z, w0.w, w1.x, w1.y, w1.z, w1.w};
#pragma unroll
    for (int cc = 0; cc < 8; ++cc)
#pragma unroll
      for (int nn = 0; nn < 4; ++nn) acc[cc][nn] += wa[cc] * xa[nn];
  }

#pragma unroll
  for (int cc = 0; cc < 8; ++cc) {
    const int c = c0 + cc;
    const float4 xr = *reinterpret_cast<const float4*>(&xt[c][m0]);
    const float bb = bl[c];
    float4 o;
    o.x = acc[cc][0] + xr.x + bb;
    o.y = acc[cc][1] + xr.y + bb;
    o.z = acc[cc][2] + xr.z + bb;
    o.w = acc[cc][3] + xr.w + bb;
    *reinterpret_cast<float4*>(&Z[(size_t)c * NPIX + n0 + m0]) = o;
  }
}

extern "C" void kernel_launch(void* const* d_in, const int* in_sizes, int n_in,
                              void* d_out, int out_size, void* d_ws,
                              size_t ws_size, hipStream_t stream) {
  (void)in_sizes; (void)n_in; (void)out_size;
  const float* x  = (const float*)d_in[0];
  const float* tw = (const float*)d_in[1];
  const float* tb = (const float*)d_in[2];
  const float* pw = (const float*)d_in[3];
  const float* pb = (const float*)d_in[4];
  const float* gw = (const float*)d_in[5];
  const float* gb = (const float*)d_in[6];
  const float* rw = (const float*)d_in[7];
  const float* rb = (const float*)d_in[8];
  float* z = (float*)d_out;

  // choose chunk count to fit workspace (NPIX/nch stays a multiple of 16)
  int nch = 64;
  auto bytes_needed = [](int nc) {
    const size_t f =
        (size_t)BB * nc * (CC * CC + CC) + 2ull * BB * (CC * CC + CC);
    return f * sizeof(float);
  };
  while (nch > 1 && bytes_needed(nch) > ws_size) nch >>= 1;
  const int chunk = NPIX / nch;

  float* Spart = (float*)d_ws;
  float* rpart = Spart + (size_t)BB * nch * CC * CC;
  float* Sf    = rpart + (size_t)BB * nch * CC;
  float* rf    = Sf + BB * CC * CC;
  float* Wcb   = rf + BB * CC;
  float* bcb   = Wcb + BB * CC * CC;

  hipLaunchKernelGGL(k1_stats, dim3(BB * nch), dim3(256), 0, stream,
                     x, Spart, rpart, nch, chunk);
  hipLaunchKernelGGL(k_reduce, dim3(BB * 16), dim3(256), 0, stream,
                     Spart, rpart, Sf, rf, nch);
  hipLaunchKernelGGL(k2_weights, dim3(BB), dim3(256), 0, stream,
                     Sf, rf, tw, tb, pw, pb, gw, gb, rw, rb, Wcb, bcb);
  hipLaunchKernelGGL(k3_apply, dim3(BB * (NPIX / TN)), dim3(256), 0, stream,
                     x, Wcb, bcb, z);
}